// Round 3
// baseline (4227.665 us; speedup 1.0000x reference)
//
#include <hip/hip_runtime.h>
#include <hip/hip_bf16.h>
#include <math.h>

// ASTGCN block, MI355X. Round 2: dtype-adaptive (device probe decides fp32 vs
// bf16 input interpretation; suspected rounds 1-2 NaN = fp32 read as bf16).
// Compute pipeline identical to round 1 (audited). S stored bf16 in ws.

namespace {

constexpr int B = 16, N = 1024, F = 32, T = 24, CC = 64, CT = 64;
constexpr int FT = F * T;     // 768
constexpr int CTT = CT * T;   // 1536

struct DP { const float* f; const __hip_bfloat16* h; };

__device__ __forceinline__ float b2f(__hip_bfloat16 v) { return __bfloat162float(v); }
__device__ __forceinline__ float ld(DP p, size_t i, bool isf) {
  return isf ? p.f[i] : __bfloat162float(p.h[i]);
}

// ---------------- dtype probe ----------------
// Read first 256 values of x as fp32. fp32 data ~N(0,1): all finite & small.
// bf16-packed data reinterpreted as fp32: exponent field doubles -> |v|~1e30+.
__global__ void k_probe(const void* x, float* flag) {
  __shared__ int cnt[256];
  int tid = threadIdx.x;
  float v = ((const float*)x)[tid];
  int sane = (v == v && fabsf(v) < 1e6f) ? 1 : 0;
  cnt[tid] = sane;
  __syncthreads();
  for (int s = 128; s > 0; s >>= 1) {
    if (tid < s) cnt[tid] += cnt[tid + s];
    __syncthreads();
  }
  if (tid == 0) flag[0] = (cnt[0] >= 128) ? 1.f : 0.f;
}

// ---------------- temporal attention ----------------
// lhst[b,t,f] = sum_n x[b,n,f,t] * U1[n];  grid = B*T*F, block 64
__global__ void k_lhs_t(DP x, DP U1, float* lhst, const float* flag) {
  bool isf = flag[0] > 0.5f;
  int bi = blockIdx.x;                 // (b*T+t)*F + f
  int f = bi % F; int t = (bi / F) % T; int b = bi / (F * T);
  int tid = threadIdx.x;
  float acc = 0.f;
  for (int n = tid; n < N; n += 64)
    acc += ld(x, (((size_t)b * N + n) * F + f) * T + t, isf) * ld(U1, n, isf);
  #pragma unroll
  for (int off = 32; off > 0; off >>= 1) acc += __shfl_down(acc, off);
  if (tid == 0) lhst[bi] = acc;
}

// lhs2[b,t,n] = sum_f lhst[b,t,f] * U2[f,n];  grid = B*T*N/256
__global__ void k_lhs2(const float* lhst, DP U2, float* lhs2, const float* flag) {
  bool isf = flag[0] > 0.5f;
  __shared__ float ls[F];
  int tid = threadIdx.x;
  int id = blockIdx.x * 256 + tid;   // (b*T+t)*N + n  (bt uniform per block)
  int n = id % N; int bt = id / N;
  if (tid < F) ls[tid] = lhst[bt * F + tid];
  __syncthreads();
  float acc = 0.f;
  #pragma unroll
  for (int f = 0; f < F; ++f) acc += ls[f] * ld(U2, f * N + n, isf);
  lhs2[id] = acc;
}

// rhst[b,n,t] = sum_f U3[f]*x[b,n,f,t];  w3x[b,n,t] = sum_f W3[f]*x[b,n,f,t]
// grid = B*N*T/256
__global__ void k_fx(DP x, DP U3, DP W3, float* rhst, float* w3x, const float* flag) {
  bool isf = flag[0] > 0.5f;
  __shared__ float u3s[F], w3s[F];
  int tid = threadIdx.x;
  if (tid < F) { u3s[tid] = ld(U3, tid, isf); w3s[tid] = ld(W3, tid, isf); }
  __syncthreads();
  int id = blockIdx.x * 256 + tid;     // (b*N+n)*T + t
  int t = id % T; int bn = id / T;
  float au = 0.f, aw = 0.f;
  #pragma unroll
  for (int f = 0; f < F; ++f) {
    float v = ld(x, ((size_t)bn * F + f) * T + t, isf);
    au += u3s[f] * v; aw += w3s[f] * v;
  }
  rhst[id] = au; w3x[id] = aw;
}

// Elog[b,t,s] = sum_n lhs2[b,t,n] * rhst[b,n,s];  grid = B*T*T, block 64
__global__ void k_Elog(const float* lhs2, const float* rhst, float* Elog) {
  int bi = blockIdx.x;                 // (b*T+t)*T + s
  int s = bi % T; int t = (bi / T) % T; int b = bi / (T * T);
  int tid = threadIdx.x;
  float acc = 0.f;
  for (int n = tid; n < N; n += 64)
    acc += lhs2[(b * T + t) * N + n] * rhst[(b * N + n) * T + s];
  #pragma unroll
  for (int off = 32; off > 0; off >>= 1) acc += __shfl_down(acc, off);
  if (tid == 0) Elog[bi] = acc;
}

// softmax over t (axis=1) for each (b,s);  grid = B, block 64
__global__ void k_Esm(const float* Elog, float* E) {
  int b = blockIdx.x; int s = threadIdx.x;
  if (s >= T) return;
  float mx = -1e30f;
  for (int t = 0; t < T; ++t) mx = fmaxf(mx, Elog[(b * T + t) * T + s]);
  float sum = 0.f;
  for (int t = 0; t < T; ++t) sum += expf(Elog[(b * T + t) * T + s] - mx);
  float inv = 1.f / sum;
  for (int t = 0; t < T; ++t)
    E[(b * T + t) * T + s] = expf(Elog[(b * T + t) * T + s] - mx) * inv;
}

// EW1[b,t] = sum_s E[b,t,s]*W1[s];  grid = B, block 64
__global__ void k_EW1(const float* E, DP W1, float* EW1, const float* flag) {
  bool isf = flag[0] > 0.5f;
  int b = blockIdx.x; int t = threadIdx.x;
  if (t >= T) return;
  float acc = 0.f;
  for (int s = 0; s < T; ++s) acc += E[(b * T + t) * T + s] * ld(W1, s, isf);
  EW1[b * T + t] = acc;
}

// ---------------- spatial attention (x_TAt never materialized) ----------------
// tmp1[b,n,f] = sum_t x[b,n,f,t]*EW1[b,t];  grid = B*N*F/256
__global__ void k_tmp1x(DP x, const float* EW1, float* tmp1, const float* flag) {
  bool isf = flag[0] > 0.5f;
  __shared__ float ew[T];
  int tid = threadIdx.x;
  int id = blockIdx.x * 256 + tid;       // (b*N+n)*F + f  (b uniform per block)
  int b = id / (N * F);
  if (tid < T) ew[tid] = EW1[b * T + tid];
  __syncthreads();
  size_t base = (size_t)id * T;
  float acc = 0.f;
  if (isf) {
    #pragma unroll
    for (int t = 0; t < T; ++t) acc += x.f[base + t] * ew[t];
  } else {
    #pragma unroll
    for (int t = 0; t < T; ++t) acc += b2f(x.h[base + t]) * ew[t];
  }
  tmp1[id] = acc;
}

// lhss[b,n,t] = sum_f tmp1[b,n,f]*W2[f,t];  grid = B*N*T/256
__global__ void k_lhs_s(const float* tmp1, DP W2, float* lhss, const float* flag) {
  bool isf = flag[0] > 0.5f;
  int id = blockIdx.x * 256 + threadIdx.x;
  int t = id % T; int bn = id / T;
  float acc = 0.f;
  #pragma unroll
  for (int f = 0; f < F; ++f) acc += tmp1[bn * F + f] * ld(W2, f * T + t, isf);
  lhss[id] = acc;
}

// rhss[b,t,m] = sum_t' w3x[b,m,t'] * E[b,t',t];  grid = B*T*N/256
__global__ void k_rhss(const float* w3x, const float* E, float* rhss) {
  __shared__ float Ec[T];
  int tid = threadIdx.x;
  int id = blockIdx.x * 256 + tid;       // (b*T+t)*N + m  (t,b uniform per block)
  int m = id % N; int t = (id / N) % T; int b = id / (N * T);
  if (tid < T) Ec[tid] = E[(b * T + tid) * T + t];
  __syncthreads();
  const float* wr = w3x + ((size_t)b * N + m) * T;
  float acc = 0.f;
  #pragma unroll
  for (int tp = 0; tp < T; ++tp) acc += wr[tp] * Ec[tp];
  rhss[id] = acc;
}

// Slog[b,n,m] = sum_t lhss[b,n,t]*rhss[b,t,m]  -> bf16 logits in ws
// grid = (N/256, N/16, B), block 256
__global__ void k_Slog(const float* lhss, const float* rhss, __hip_bfloat16* S) {
  __shared__ float rt[T][256];
  __shared__ float lt[16][T];
  int m0 = blockIdx.x * 256, n0 = blockIdx.y * 16, b = blockIdx.z;
  int tid = threadIdx.x;
  for (int t = 0; t < T; ++t) rt[t][tid] = rhss[((size_t)b * T + t) * N + m0 + tid];
  for (int i = tid; i < 16 * T; i += 256) {
    int n = i / T, t = i % T;
    lt[n][t] = lhss[((size_t)b * N + n0 + n) * T + t];
  }
  __syncthreads();
  #pragma unroll 4
  for (int n = 0; n < 16; ++n) {
    float acc = 0.f;
    #pragma unroll
    for (int t = 0; t < T; ++t) acc += lt[n][t] * rt[t][tid];
    S[((size_t)b * N + n0 + n) * N + m0 + tid] = __float2bfloat16(acc);
  }
}

// in-place column softmax over n (axis=1) for each (b,m); bf16 -> bf16
// grid = (N/256, B), block 256
__global__ void k_Ssm3(__hip_bfloat16* S) {
  int m = blockIdx.x * 256 + threadIdx.x; int b = blockIdx.y;
  size_t base = (size_t)b * N * N + m;
  float mx = -1e30f;
  for (int n = 0; n < N; ++n) mx = fmaxf(mx, b2f(S[base + (size_t)n * N]));
  float sum = 0.f;
  for (int n = 0; n < N; ++n) sum += expf(b2f(S[base + (size_t)n * N]) - mx);
  float inv = 1.f / sum;
  for (int n = 0; n < N; ++n) {
    size_t i = base + (size_t)n * N;
    S[i] = __float2bfloat16(expf(b2f(S[i]) - mx) * inv);
  }
}

// ---------------- Chebyshev contraction (dominant GEMM) ----------------
// rhs_k[bl,m,c] = sum_n (cheb[k,n,m]*S[b,n,m]) * x[b,n,c],  c=(f,t) in [0,768)
// grid = (768/64, N/64, Bc), block 256 (16x16 threads, 4x4 per thread)
__global__ __launch_bounds__(256) void k_gemm(DP cheb, const __hip_bfloat16* S,
                                              DP x, float* rhs, int k, int b0,
                                              const float* flag) {
  bool isf = flag[0] > 0.5f;
  __shared__ float As[16][64];
  __shared__ float Xs[16][64];
  int bl = blockIdx.z, b = b0 + bl;
  int m0 = blockIdx.y * 64, c0 = blockIdx.x * 64;
  int tid = threadIdx.x, tx = tid % 16, ty = tid / 16;
  int lr = tid / 64, lc = tid % 64;
  float acc[4][4] = {};
  for (int n0 = 0; n0 < N; n0 += 16) {
    if (isf) {
      #pragma unroll
      for (int i = 0; i < 4; ++i) {
        int n = n0 + lr + i * 4;
        As[lr + i * 4][lc] = x.f == nullptr ? 0.f :  // keep shape; never null
            cheb.f[((size_t)k * N + n) * N + m0 + lc] *
            b2f(S[((size_t)b * N + n) * N + m0 + lc]);
        Xs[lr + i * 4][lc] = x.f[((size_t)b * N + n) * FT + c0 + lc];
      }
    } else {
      #pragma unroll
      for (int i = 0; i < 4; ++i) {
        int n = n0 + lr + i * 4;
        As[lr + i * 4][lc] = b2f(cheb.h[((size_t)k * N + n) * N + m0 + lc]) *
                             b2f(S[((size_t)b * N + n) * N + m0 + lc]);
        Xs[lr + i * 4][lc] = b2f(x.h[((size_t)b * N + n) * FT + c0 + lc]);
      }
    }
    __syncthreads();
    #pragma unroll
    for (int n = 0; n < 16; ++n) {
      float4 a = *(const float4*)&As[n][ty * 4];
      float4 xv = *(const float4*)&Xs[n][tx * 4];
      acc[0][0] += a.x * xv.x; acc[0][1] += a.x * xv.y; acc[0][2] += a.x * xv.z; acc[0][3] += a.x * xv.w;
      acc[1][0] += a.y * xv.x; acc[1][1] += a.y * xv.y; acc[1][2] += a.y * xv.z; acc[1][3] += a.y * xv.w;
      acc[2][0] += a.z * xv.x; acc[2][1] += a.z * xv.y; acc[2][2] += a.z * xv.z; acc[2][3] += a.z * xv.w;
      acc[3][0] += a.w * xv.x; acc[3][1] += a.w * xv.y; acc[3][2] += a.w * xv.z; acc[3][3] += a.w * xv.w;
    }
    __syncthreads();
  }
  #pragma unroll
  for (int i = 0; i < 4; ++i) {
    float4 v = make_float4(acc[i][0], acc[i][1], acc[i][2], acc[i][3]);
    *(float4*)&rhs[((size_t)bl * N + m0 + ty * 4 + i) * FT + c0 + tx * 4] = v;
  }
}

// sg[bl,m,o,t] (+)= sum_f rhs_k[bl,m,f,t] * Theta[k,f,o]; relu at k==2
// grid = Bc*N, block 64 (lane = o)
__global__ __launch_bounds__(64) void k_theta(const float* rhsk, DP Theta,
                                              float* sg, int k, const float* flag) {
  bool isf = flag[0] > 0.5f;
  __shared__ float row[FT];
  int bm = blockIdx.x; int o = threadIdx.x;
  for (int i = o; i < FT; i += 64) row[i] = rhsk[(size_t)bm * FT + i];
  float th[F];
  #pragma unroll
  for (int f = 0; f < F; ++f) th[f] = ld(Theta, (k * F + f) * CC + o, isf);
  __syncthreads();
  float acc[T];
  #pragma unroll
  for (int t = 0; t < T; ++t) acc[t] = 0.f;
  #pragma unroll
  for (int f = 0; f < F; ++f) {
    #pragma unroll
    for (int t = 0; t < T; ++t) acc[t] += th[f] * row[f * T + t];
  }
  float* p = sg + (size_t)bm * (CC * T) + o * T;
  if (k == 0) {
    #pragma unroll
    for (int t = 0; t < T; ++t) p[t] = acc[t];
  } else if (k == 1) {
    #pragma unroll
    for (int t = 0; t < T; ++t) p[t] += acc[t];
  } else {
    #pragma unroll
    for (int t = 0; t < T; ++t) p[t] = fmaxf(p[t] + acc[t], 0.f);
  }
}

// ---------------- time conv + residual + relu + layernorm ----------------
// grid = Bc*N, block 64 (lane = ct)
__global__ __launch_bounds__(64) void k_final(const float* sg, DP x, DP tcw,
                                              DP tcb, DP rcw, DP rcb,
                                              DP gam, DP bet,
                                              void* out, int b0, const float* flag) {
  bool isf = flag[0] > 0.5f;
  __shared__ float sgs[CC * T];
  __shared__ float xs[F * T];
  __shared__ float zs[CT * (T + 1)];
  __shared__ float mu[T], rs[T];
  int bm = blockIdx.x; int ct = threadIdx.x;
  size_t grow = (size_t)b0 * N + bm;     // global (b*N+m)
  for (int i = ct; i < CC * T; i += 64) sgs[i] = sg[(size_t)bm * (CC * T) + i];
  for (int i = ct; i < F * T; i += 64) xs[i] = ld(x, grow * FT + i, isf);
  __syncthreads();

  float acc[T];
  float bias = ld(tcb, ct, isf) + ld(rcb, ct, isf);
  #pragma unroll
  for (int t = 0; t < T; ++t) acc[t] = bias;

  // time conv (1,3), pad (0,1)
  size_t wbase = (size_t)ct * CC * 3;
  for (int cc = 0; cc < CC; ++cc) {
    float w0 = ld(tcw, wbase + cc * 3 + 0, isf);
    float w1 = ld(tcw, wbase + cc * 3 + 1, isf);
    float w2 = ld(tcw, wbase + cc * 3 + 2, isf);
    const float* srow = &sgs[cc * T];
    #pragma unroll
    for (int t = 0; t < T; ++t) {
      float v = w1 * srow[t];
      if (t > 0) v += w0 * srow[t - 1];
      if (t < T - 1) v += w2 * srow[t + 1];
      acc[t] += v;
    }
  }
  // residual 1x1 conv
  #pragma unroll
  for (int f = 0; f < F; ++f) {
    float w = ld(rcw, (size_t)ct * F + f, isf);
    const float* xr = &xs[f * T];
    #pragma unroll
    for (int t = 0; t < T; ++t) acc[t] += w * xr[t];
  }
  #pragma unroll
  for (int t = 0; t < T; ++t) zs[ct * (T + 1) + t] = fmaxf(acc[t], 0.f);
  __syncthreads();
  if (ct < T) {
    int t = ct;
    float s = 0.f;
    for (int c = 0; c < CT; ++c) s += zs[c * (T + 1) + t];
    float m = s * (1.f / CT);
    float v = 0.f;
    for (int c = 0; c < CT; ++c) { float d = zs[c * (T + 1) + t] - m; v += d * d; }
    mu[t] = m; rs[t] = rsqrtf(v * (1.f / CT) + 1e-5f);
  }
  __syncthreads();
  float g = ld(gam, ct, isf), be = ld(bet, ct, isf);
  if (isf) {
    float* orow = (float*)out + grow * CTT + ct * T;
    #pragma unroll
    for (int t = 0; t < T; ++t)
      orow[t] = (zs[ct * (T + 1) + t] - mu[t]) * rs[t] * g + be;
  } else {
    __hip_bfloat16* orow = (__hip_bfloat16*)out + grow * CTT + ct * T;
    #pragma unroll
    for (int t = 0; t < T; ++t)
      orow[t] = __float2bfloat16((zs[ct * (T + 1) + t] - mu[t]) * rs[t] * g + be);
  }
}

}  // namespace

extern "C" void kernel_launch(void* const* d_in, const int* in_sizes, int n_in,
                              void* d_out, int out_size, void* d_ws, size_t ws_size,
                              hipStream_t stream) {
  (void)in_sizes; (void)n_in; (void)out_size;
  auto dp = [&](int i) {
    DP p; p.f = (const float*)d_in[i]; p.h = (const __hip_bfloat16*)d_in[i]; return p;
  };
  DP x = dp(0), W1 = dp(1), W2 = dp(2), W3 = dp(3), U1 = dp(4), U2 = dp(5),
     U3 = dp(6), cheb = dp(7), Theta = dp(8), tcw = dp(9), tcb = dp(10),
     rcw = dp(11), rcb = dp(12), gam = dp(13), bet = dp(14);

  // ---- runtime-adaptive workspace layout ----
  const size_t FLAG_BYTES = 256;
  const size_t SB_BYTES = (size_t)B * N * N * 2;          // 33,554,432 (S bf16)
  const size_t SG_PER_B = (size_t)N * CC * T * 4;         // 6,291,456
  const size_t RK_PER_B = (size_t)N * FT * 4;             // 3,145,728
  const size_t SMALL_FLOATS = 2521472;                    // 10,085,888 B
  int Bc = 8;
  while (Bc > 1 && FLAG_BYTES + SB_BYTES + (size_t)Bc * (SG_PER_B + RK_PER_B) +
                       SMALL_FLOATS * 4 > ws_size)
    Bc >>= 1;

  char* w = (char*)d_ws;
  float* flag = (float*)w;
  __hip_bfloat16* Sb = (__hip_bfloat16*)(w + FLAG_BYTES);
  float* sgf  = (float*)(w + FLAG_BYTES + SB_BYTES);
  float* rhsk = (float*)(w + FLAG_BYTES + SB_BYTES + (size_t)Bc * SG_PER_B);
  float* sm   = (float*)(w + FLAG_BYTES + SB_BYTES + (size_t)Bc * (SG_PER_B + RK_PER_B));
  float* lhst = sm;                       // B*T*F   = 12288
  float* lhs2 = lhst + B * T * F;         // B*T*N   = 393216
  float* rhst = lhs2 + B * T * N;         // B*N*T   = 393216
  float* w3x  = rhst + B * N * T;         // B*N*T   = 393216
  float* Elog = w3x + B * N * T;          // B*T*T   = 9216
  float* E    = Elog + B * T * T;         // B*T*T   = 9216
  float* EW1  = E + B * T * T;            // B*T     = 384
  float* tmp1 = EW1 + B * T;              // B*N*F   = 524288
  float* lhss = tmp1 + B * N * F;         // B*N*T   = 393216
  float* rhss = lhss + B * N * T;         // B*N*T   = 393216

  // dtype probe
  k_probe<<<1, 256, 0, stream>>>(d_in[0], flag);

  // temporal attention
  k_lhs_t<<<B * T * F, 64, 0, stream>>>(x, U1, lhst, flag);
  k_lhs2<<<(B * T * N) / 256, 256, 0, stream>>>(lhst, U2, lhs2, flag);
  k_fx<<<(B * N * T) / 256, 256, 0, stream>>>(x, U3, W3, rhst, w3x, flag);
  k_Elog<<<B * T * T, 64, 0, stream>>>(lhs2, rhst, Elog);
  k_Esm<<<B, 64, 0, stream>>>(Elog, E);
  k_EW1<<<B, 64, 0, stream>>>(E, W1, EW1, flag);

  // spatial attention (x_TAt folded out)
  k_tmp1x<<<(B * N * F) / 256, 256, 0, stream>>>(x, EW1, tmp1, flag);
  k_lhs_s<<<(B * N * T) / 256, 256, 0, stream>>>(tmp1, W2, lhss, flag);
  k_rhss<<<(B * N * T) / 256, 256, 0, stream>>>(w3x, E, rhss);
  k_Slog<<<dim3(N / 256, N / 16, B), 256, 0, stream>>>(lhss, rhss, Sb);
  k_Ssm3<<<dim3(N / 256, B), 256, 0, stream>>>(Sb);

  // chebyshev graph conv + theta + final, chunked over b to fit workspace
  for (int b0 = 0; b0 < B; b0 += Bc) {
    for (int k = 0; k < 3; ++k) {
      k_gemm<<<dim3(FT / 64, N / 64, Bc), 256, 0, stream>>>(cheb, Sb, x, rhsk,
                                                            k, b0, flag);
      k_theta<<<Bc * N, 64, 0, stream>>>(rhsk, Theta, sgf, k, flag);
    }
    k_final<<<Bc * N, 64, 0, stream>>>(sgf, x, tcw, tcb, rcw, rcb,
                                       gam, bet, d_out, b0, flag);
  }
}

// Round 4
// 1801.385 us; speedup vs baseline: 2.3469x; 2.3469x over previous
//
#include <hip/hip_runtime.h>
#include <hip/hip_bf16.h>
#include <math.h>

// ASTGCN block, MI355X. Round 4: fp32 confirmed (round-3 pass). MFMA bf16 for
// the dominant Chebyshev GEMM; k_final rewritten (LDS-staged weights, wave-LN,
// no spills); k_theta fused over k (no global RMW).

namespace {

constexpr int B = 16, N = 1024, F = 32, T = 24, CC = 64, CT = 64;
constexpr int FT = F * T;     // 768
constexpr int CTT = CT * T;   // 1536

using f32x4  = __attribute__((ext_vector_type(4))) float;
using short8 = __attribute__((ext_vector_type(8))) short;

__device__ __forceinline__ float b2f(__hip_bfloat16 v) { return __bfloat162float(v); }
__device__ __forceinline__ unsigned short f2bu(float x) {   // fp32 -> bf16 bits, RNE
  union { float f; unsigned u; } c; c.f = x;
  unsigned u = c.u;
  return (unsigned short)((u + 0x7FFFu + ((u >> 16) & 1u)) >> 16);
}
__device__ __forceinline__ float us2f(unsigned short u) {   // bf16 bits -> fp32
  union { unsigned u; float f; } c; c.u = ((unsigned)u) << 16; return c.f;
}

// ---------------- temporal attention ----------------
// lhst[b,t,f] = sum_n x[b,n,f,t] * U1[n];  grid = B*T*F, block 64
__global__ void k_lhs_t(const float* x, const float* U1, float* lhst) {
  int bi = blockIdx.x;                 // (b*T+t)*F + f
  int f = bi % F; int t = (bi / F) % T; int b = bi / (F * T);
  int tid = threadIdx.x;
  float acc = 0.f;
  for (int n = tid; n < N; n += 64)
    acc += x[(((size_t)b * N + n) * F + f) * T + t] * U1[n];
  #pragma unroll
  for (int off = 32; off > 0; off >>= 1) acc += __shfl_down(acc, off);
  if (tid == 0) lhst[bi] = acc;
}

// lhs2[b,t,n] = sum_f lhst[b,t,f] * U2[f,n];  grid = B*T*N/256
__global__ void k_lhs2(const float* lhst, const float* U2, float* lhs2) {
  __shared__ float ls[F];
  int tid = threadIdx.x;
  int id = blockIdx.x * 256 + tid;   // (b*T+t)*N + n  (bt uniform per block)
  int n = id % N; int bt = id / N;
  if (tid < F) ls[tid] = lhst[bt * F + tid];
  __syncthreads();
  float acc = 0.f;
  #pragma unroll
  for (int f = 0; f < F; ++f) acc += ls[f] * U2[f * N + n];
  lhs2[id] = acc;
}

// rhst[b,n,t] = sum_f U3[f]*x[b,n,f,t];  w3x[b,n,t] = sum_f W3[f]*x[b,n,f,t]
// grid = B*N*T/256
__global__ void k_fx(const float* x, const float* U3, const float* W3,
                     float* rhst, float* w3x) {
  __shared__ float u3s[F], w3s[F];
  int tid = threadIdx.x;
  if (tid < F) { u3s[tid] = U3[tid]; w3s[tid] = W3[tid]; }
  __syncthreads();
  int id = blockIdx.x * 256 + tid;     // (b*N+n)*T + t
  int t = id % T; int bn = id / T;
  float au = 0.f, aw = 0.f;
  #pragma unroll
  for (int f = 0; f < F; ++f) {
    float v = x[((size_t)bn * F + f) * T + t];
    au += u3s[f] * v; aw += w3s[f] * v;
  }
  rhst[id] = au; w3x[id] = aw;
}

// Elog[b,t,s] = sum_n lhs2[b,t,n] * rhst[b,n,s];  grid = B*T*T, block 64
__global__ void k_Elog(const float* lhs2, const float* rhst, float* Elog) {
  int bi = blockIdx.x;                 // (b*T+t)*T + s
  int s = bi % T; int t = (bi / T) % T; int b = bi / (T * T);
  int tid = threadIdx.x;
  float acc = 0.f;
  for (int n = tid; n < N; n += 64)
    acc += lhs2[(b * T + t) * N + n] * rhst[(b * N + n) * T + s];
  #pragma unroll
  for (int off = 32; off > 0; off >>= 1) acc += __shfl_down(acc, off);
  if (tid == 0) Elog[bi] = acc;
}

// softmax over t (axis=1) for each (b,s);  grid = B, block 64
__global__ void k_Esm(const float* Elog, float* E) {
  int b = blockIdx.x; int s = threadIdx.x;
  if (s >= T) return;
  float mx = -1e30f;
  for (int t = 0; t < T; ++t) mx = fmaxf(mx, Elog[(b * T + t) * T + s]);
  float sum = 0.f;
  for (int t = 0; t < T; ++t) sum += expf(Elog[(b * T + t) * T + s] - mx);
  float inv = 1.f / sum;
  for (int t = 0; t < T; ++t)
    E[(b * T + t) * T + s] = expf(Elog[(b * T + t) * T + s] - mx) * inv;
}

// EW1[b,t] = sum_s E[b,t,s]*W1[s];  grid = B, block 64
__global__ void k_EW1(const float* E, const float* W1, float* EW1) {
  int b = blockIdx.x; int t = threadIdx.x;
  if (t >= T) return;
  float acc = 0.f;
  for (int s = 0; s < T; ++s) acc += E[(b * T + t) * T + s] * W1[s];
  EW1[b * T + t] = acc;
}

// ---------------- spatial attention (x_TAt never materialized) ----------------
// tmp1[b,n,f] = sum_t x[b,n,f,t]*EW1[b,t];  grid = B*N*F/256
__global__ void k_tmp1x(const float* x, const float* EW1, float* tmp1) {
  __shared__ float ew[T];
  int tid = threadIdx.x;
  int id = blockIdx.x * 256 + tid;       // (b*N+n)*F + f  (b uniform per block)
  int b = id / (N * F);
  if (tid < T) ew[tid] = EW1[b * T + tid];
  __syncthreads();
  const float* xr = x + (size_t)id * T;
  float acc = 0.f;
  #pragma unroll
  for (int t = 0; t < T; ++t) acc += xr[t] * ew[t];
  tmp1[id] = acc;
}

// lhss[b,n,t] = sum_f tmp1[b,n,f]*W2[f,t];  grid = B*N*T/256
__global__ void k_lhs_s(const float* tmp1, const float* W2, float* lhss) {
  int id = blockIdx.x * 256 + threadIdx.x;
  int t = id % T; int bn = id / T;
  float acc = 0.f;
  #pragma unroll
  for (int f = 0; f < F; ++f) acc += tmp1[bn * F + f] * W2[f * T + t];
  lhss[id] = acc;
}

// rhss[b,t,m] = sum_t' w3x[b,m,t'] * E[b,t',t];  grid = B*T*N/256
__global__ void k_rhss(const float* w3x, const float* E, float* rhss) {
  __shared__ float Ec[T];
  int tid = threadIdx.x;
  int id = blockIdx.x * 256 + tid;       // (b*T+t)*N + m  (t,b uniform per block)
  int m = id % N; int t = (id / N) % T; int b = id / (N * T);
  if (tid < T) Ec[tid] = E[(b * T + tid) * T + t];
  __syncthreads();
  const float* wr = w3x + ((size_t)b * N + m) * T;
  float acc = 0.f;
  #pragma unroll
  for (int tp = 0; tp < T; ++tp) acc += wr[tp] * Ec[tp];
  rhss[id] = acc;
}

// Slog[b,n,m] = sum_t lhss[b,n,t]*rhss[b,t,m]  -> bf16 logits in ws
// grid = (N/256, N/16, B), block 256
__global__ void k_Slog(const float* lhss, const float* rhss, __hip_bfloat16* S) {
  __shared__ float rt[T][256];
  __shared__ float lt[16][T];
  int m0 = blockIdx.x * 256, n0 = blockIdx.y * 16, b = blockIdx.z;
  int tid = threadIdx.x;
  for (int t = 0; t < T; ++t) rt[t][tid] = rhss[((size_t)b * T + t) * N + m0 + tid];
  for (int i = tid; i < 16 * T; i += 256) {
    int n = i / T, t = i % T;
    lt[n][t] = lhss[((size_t)b * N + n0 + n) * T + t];
  }
  __syncthreads();
  #pragma unroll 4
  for (int n = 0; n < 16; ++n) {
    float acc = 0.f;
    #pragma unroll
    for (int t = 0; t < T; ++t) acc += lt[n][t] * rt[t][tid];
    S[((size_t)b * N + n0 + n) * N + m0 + tid] = __float2bfloat16(acc);
  }
}

// in-place column softmax over n (axis=1) for each (b,m); bf16 -> bf16
// grid = (N/256, B), block 256
__global__ void k_Ssm3(__hip_bfloat16* S) {
  int m = blockIdx.x * 256 + threadIdx.x; int b = blockIdx.y;
  size_t base = (size_t)b * N * N + m;
  float mx = -1e30f;
  for (int n = 0; n < N; ++n) mx = fmaxf(mx, b2f(S[base + (size_t)n * N]));
  float sum = 0.f;
  for (int n = 0; n < N; ++n) sum += expf(b2f(S[base + (size_t)n * N]) - mx);
  float inv = 1.f / sum;
  for (int n = 0; n < N; ++n) {
    size_t i = base + (size_t)n * N;
    S[i] = __float2bfloat16(expf(b2f(S[i]) - mx) * inv);
  }
}

// ---------------- Chebyshev contraction: MFMA bf16 ----------------
// rhs[bl,m,c] = sum_n (cheb[k,n,m]*S[b,n,m]) * x[b,n,c]
// Tile: M=64 (m), NC=128 (c), KT=64 (n). grid = (768/128, 1024/64, Bc), block 256.
// A_lds[m][n] and X_lds[c][n] k-contiguous, row stride 72 bf16 (b128-aligned,
// 2-way banks on frag reads). 4 waves; wave w covers c in [w*32, w*32+32).
__global__ __launch_bounds__(256) void k_gemm(const float* cheb,
                                              const __hip_bfloat16* S,
                                              const float* x, float* rhs,
                                              int k, int b0) {
  __shared__ unsigned short A_l[64 * 72];
  __shared__ unsigned short X_l[128 * 72];
  int bl = blockIdx.z, b = b0 + bl;
  int m0 = blockIdx.y * 64, c0 = blockIdx.x * 128;
  int tid = threadIdx.x;
  int lane = tid & 63, wid = tid >> 6;
  int l15 = tid & 15, quad = lane >> 4;

  // staging maps
  int am = tid & 63, anq = tid >> 6;     // A: lane=m (coalesced), 16 n each
  int xc = tid & 127, xnh = tid >> 7;    // X: lane=c (coalesced), 32 n each

  f32x4 acc[4][2];
  #pragma unroll
  for (int i = 0; i < 4; ++i)
    #pragma unroll
    for (int j = 0; j < 2; ++j) acc[i][j] = (f32x4){0.f, 0.f, 0.f, 0.f};

  for (int n0 = 0; n0 < N; n0 += 64) {
    // stage A = cheb*S (bf16), transposed to [m][n]
    #pragma unroll
    for (int p = 0; p < 8; ++p) {
      int nl = anq * 16 + 2 * p;
      size_t g0 = ((size_t)k * N + n0 + nl) * N + m0 + am;
      size_t s0 = ((size_t)b * N + n0 + nl) * N + m0 + am;
      float v0 = cheb[g0] * b2f(S[s0]);
      float v1 = cheb[g0 + N] * b2f(S[s0 + N]);
      *(unsigned*)&A_l[am * 72 + nl] = (unsigned)f2bu(v0) | ((unsigned)f2bu(v1) << 16);
    }
    // stage X (bf16), transposed to [c][n]
    #pragma unroll
    for (int p = 0; p < 16; ++p) {
      int nl = xnh * 32 + 2 * p;
      size_t g0 = ((size_t)b * N + n0 + nl) * FT + c0 + xc;
      float v0 = x[g0];
      float v1 = x[g0 + FT];
      *(unsigned*)&X_l[xc * 72 + nl] = (unsigned)f2bu(v0) | ((unsigned)f2bu(v1) << 16);
    }
    __syncthreads();
    #pragma unroll
    for (int ks = 0; ks < 2; ++ks) {
      int nf = ks * 32 + quad * 8;
      short8 af[4], bf[2];
      #pragma unroll
      for (int mt = 0; mt < 4; ++mt)
        af[mt] = *(const short8*)&A_l[(mt * 16 + l15) * 72 + nf];
      #pragma unroll
      for (int ct = 0; ct < 2; ++ct)
        bf[ct] = *(const short8*)&X_l[(wid * 32 + ct * 16 + l15) * 72 + nf];
      #pragma unroll
      for (int mt = 0; mt < 4; ++mt)
        #pragma unroll
        for (int ct = 0; ct < 2; ++ct)
          acc[mt][ct] = __builtin_amdgcn_mfma_f32_16x16x32_bf16(
              af[mt], bf[ct], acc[mt][ct], 0, 0, 0);
    }
    __syncthreads();
  }
  // epilogue: C lane map col=lane&15, row=quad*4+reg
  #pragma unroll
  for (int mt = 0; mt < 4; ++mt)
    #pragma unroll
    for (int ct = 0; ct < 2; ++ct) {
      int col = c0 + wid * 32 + ct * 16 + l15;
      #pragma unroll
      for (int r = 0; r < 4; ++r) {
        int row = m0 + mt * 16 + quad * 4 + r;
        rhs[((size_t)bl * N + row) * FT + col] = acc[mt][ct][r];
      }
    }
}

// sg[bl,m,o,t] = relu(sum_k sum_f rhs_k[bl,m,f,t] * Theta[k,f,o])
// grid = Bc*N, block 64 (lane = o)
__global__ __launch_bounds__(64) void k_theta3(const float* r0, const float* r1,
                                               const float* r2, const float* Theta,
                                               float* sg) {
  __shared__ float row[3][FT];
  int bm = blockIdx.x; int o = threadIdx.x;
  for (int i = o; i < FT; i += 64) {
    row[0][i] = r0[(size_t)bm * FT + i];
    row[1][i] = r1[(size_t)bm * FT + i];
    row[2][i] = r2[(size_t)bm * FT + i];
  }
  __syncthreads();
  float acc[T];
  #pragma unroll
  for (int t = 0; t < T; ++t) acc[t] = 0.f;
  for (int k = 0; k < 3; ++k) {
    #pragma unroll
    for (int f = 0; f < F; ++f) {
      float th = Theta[(k * F + f) * CC + o];
      const float4* rp = (const float4*)&row[k][f * T];
      #pragma unroll
      for (int q = 0; q < 6; ++q) {
        float4 v = rp[q];
        acc[q * 4 + 0] += th * v.x; acc[q * 4 + 1] += th * v.y;
        acc[q * 4 + 2] += th * v.z; acc[q * 4 + 3] += th * v.w;
      }
    }
  }
  float* p = sg + (size_t)bm * CTT + o * T;
  #pragma unroll
  for (int t = 0; t < T; ++t) p[t] = fmaxf(acc[t], 0.f);
}

// ---------------- time conv + residual + relu + layernorm ----------------
// block 256 = 4 waves = 4 rows; lane = ct. LN across the 64 lanes via shfl_xor.
// grid = Bc*N/4
__global__ __launch_bounds__(256) void k_final(const float* sg, const float* x,
                                               const float* tcw, const float* tcb,
                                               const float* rcw, const float* rcb,
                                               const float* gam, const float* bet,
                                               float* out, int b0) {
  __shared__ unsigned short tcw_l[192 * 65];   // [cc*3+j][ct] bf16, pad 65
  __shared__ float rcw_l[32 * 65];             // [f][ct] fp32, pad 65
  __shared__ float sgs[4][CC * T];             // 4 rows
  __shared__ unsigned short xs[4 * F * T];     // 4 rows bf16
  int tid = threadIdx.x;
  int w = tid >> 6, ct = tid & 63;
  int row_l0 = blockIdx.x * 4;                 // chunk-local row base

  for (int g = tid; g < CT * CC * 3; g += 256) {
    int c = g / 192, r = g % 192;
    tcw_l[r * 65 + c] = f2bu(tcw[g]);
  }
  for (int g = tid; g < CT * F; g += 256) {
    int c = g / F, f = g % F;
    rcw_l[f * 65 + c] = rcw[g];
  }
  for (int i = tid; i < 4 * CC * T; i += 256) {
    int r = i / (CC * T), j = i % (CC * T);
    sgs[r][j] = sg[(size_t)(row_l0 + r) * CTT + j];
  }
  for (int i = tid; i < 4 * FT; i += 256) {
    int r = i / FT, j = i % FT;
    xs[i] = f2bu(x[((size_t)b0 * N + row_l0 + r) * FT + j]);
  }
  __syncthreads();

  float acc[T];
  float bias = tcb[ct] + rcb[ct];
  #pragma unroll
  for (int t = 0; t < T; ++t) acc[t] = bias;

  // time conv (1,3), pad (0,1)
  for (int cc = 0; cc < CC; ++cc) {
    float w0 = us2f(tcw_l[(cc * 3 + 0) * 65 + ct]);
    float w1 = us2f(tcw_l[(cc * 3 + 1) * 65 + ct]);
    float w2 = us2f(tcw_l[(cc * 3 + 2) * 65 + ct]);
    const float4* sp = (const float4*)&sgs[w][cc * T];
    float sv[T];
    #pragma unroll
    for (int q = 0; q < 6; ++q) {
      float4 v = sp[q];
      sv[q * 4 + 0] = v.x; sv[q * 4 + 1] = v.y; sv[q * 4 + 2] = v.z; sv[q * 4 + 3] = v.w;
    }
    acc[0] += w1 * sv[0] + w2 * sv[1];
    #pragma unroll
    for (int t = 1; t < T - 1; ++t)
      acc[t] += w0 * sv[t - 1] + w1 * sv[t] + w2 * sv[t + 1];
    acc[T - 1] += w0 * sv[T - 2] + w1 * sv[T - 1];
  }
  // residual 1x1
  #pragma unroll
  for (int f = 0; f < F; ++f) {
    float wf = rcw_l[f * 65 + ct];
    const unsigned* xp = (const unsigned*)&xs[w * FT + f * T];
    #pragma unroll
    for (int j = 0; j < 12; ++j) {
      unsigned u = xp[j];
      union { unsigned u; float f; } lo, hi;
      lo.u = u << 16; hi.u = u & 0xffff0000u;
      acc[2 * j] += wf * lo.f;
      acc[2 * j + 1] += wf * hi.f;
    }
  }
  // relu + LN over ct (the 64 lanes) per t
  float g = gam[ct], be = bet[ct];
  float o[T];
  #pragma unroll
  for (int t = 0; t < T; ++t) {
    float z = fmaxf(acc[t], 0.f);
    float s = z, q = z * z;
    #pragma unroll
    for (int off = 1; off < 64; off <<= 1) {
      s += __shfl_xor(s, off);
      q += __shfl_xor(q, off);
    }
    float mu = s * (1.f / 64.f);
    float var = q * (1.f / 64.f) - mu * mu;
    o[t] = (z - mu) * rsqrtf(var + 1e-5f) * g + be;
  }
  float* orow = out + ((size_t)b0 * N + row_l0 + w) * CTT + ct * T;
  #pragma unroll
  for (int q = 0; q < 6; ++q)
    ((float4*)orow)[q] = make_float4(o[q * 4], o[q * 4 + 1], o[q * 4 + 2], o[q * 4 + 3]);
}

}  // namespace

extern "C" void kernel_launch(void* const* d_in, const int* in_sizes, int n_in,
                              void* d_out, int out_size, void* d_ws, size_t ws_size,
                              hipStream_t stream) {
  (void)in_sizes; (void)n_in; (void)out_size;
  const float* x     = (const float*)d_in[0];
  const float* W1    = (const float*)d_in[1];
  const float* W2    = (const float*)d_in[2];
  const float* W3    = (const float*)d_in[3];
  const float* U1    = (const float*)d_in[4];
  const float* U2    = (const float*)d_in[5];
  const float* U3    = (const float*)d_in[6];
  const float* cheb  = (const float*)d_in[7];
  const float* Theta = (const float*)d_in[8];
  const float* tcw   = (const float*)d_in[9];
  const float* tcb   = (const float*)d_in[10];
  const float* rcw   = (const float*)d_in[11];
  const float* rcb   = (const float*)d_in[12];
  const float* gam   = (const float*)d_in[13];
  const float* bet   = (const float*)d_in[14];
  float* out = (float*)d_out;

  // ---- runtime-adaptive workspace layout ----
  const size_t SB_BYTES = (size_t)B * N * N * 2;          // 33,554,432 (S bf16)
  const size_t SG_PER_B = (size_t)N * CC * T * 4;         // 6,291,456
  const size_t RK_PER_B = (size_t)N * FT * 4;             // 3,145,728 (x3 buffers)
  const size_t SMALL_FLOATS = 2521472;                    // 10,085,888 B
  int Bc = 16;
  while (Bc > 1 && SB_BYTES + (size_t)Bc * (SG_PER_B + 3 * RK_PER_B) +
                       SMALL_FLOATS * 4 > ws_size)
    Bc >>= 1;

  char* w = (char*)d_ws;
  __hip_bfloat16* Sb = (__hip_bfloat16*)w;
  size_t off = SB_BYTES;
  float* rk[3];
  for (int i = 0; i < 3; ++i) { rk[i] = (float*)(w + off); off += (size_t)Bc * RK_PER_B; }
  float* sgf = (float*)(w + off); off += (size_t)Bc * SG_PER_B;
  float* sm  = (float*)(w + off);
  float* lhst = sm;                       // B*T*F   = 12288
  float* lhs2 = lhst + B * T * F;         // B*T*N   = 393216
  float* rhst = lhs2 + B * T * N;         // B*N*T   = 393216
  float* w3x  = rhst + B * N * T;         // B*N*T   = 393216
  float* Elog = w3x + B * N * T;          // B*T*T   = 9216
  float* E    = Elog + B * T * T;         // B*T*T   = 9216
  float* EW1  = E + B * T * T;            // B*T     = 384
  float* tmp1 = EW1 + B * T;              // B*N*F   = 524288
  float* lhss = tmp1 + B * N * F;         // B*N*T   = 393216
  float* rhss = lhss + B * N * T;         // B*N*T   = 393216

  // temporal attention
  k_lhs_t<<<B * T * F, 64, 0, stream>>>(x, U1, lhst);
  k_lhs2<<<(B * T * N) / 256, 256, 0, stream>>>(lhst, U2, lhs2);
  k_fx<<<(B * N * T) / 256, 256, 0, stream>>>(x, U3, W3, rhst, w3x);
  k_Elog<<<B * T * T, 64, 0, stream>>>(lhs2, rhst, Elog);
  k_Esm<<<B, 64, 0, stream>>>(Elog, E);
  k_EW1<<<B, 64, 0, stream>>>(E, W1, EW1);

  // spatial attention (x_TAt folded out)
  k_tmp1x<<<(B * N * F) / 256, 256, 0, stream>>>(x, EW1, tmp1);
  k_lhs_s<<<(B * N * T) / 256, 256, 0, stream>>>(tmp1, W2, lhss);
  k_rhss<<<(B * N * T) / 256, 256, 0, stream>>>(w3x, E, rhss);
  k_Slog<<<dim3(N / 256, N / 16, B), 256, 0, stream>>>(lhss, rhss, Sb);
  k_Ssm3<<<dim3(N / 256, B), 256, 0, stream>>>(Sb);

  // chebyshev graph conv (MFMA) + fused theta + final, chunked over b
  for (int b0 = 0; b0 < B; b0 += Bc) {
    for (int k = 0; k < 3; ++k)
      k_gemm<<<dim3(FT / 128, N / 64, Bc), 256, 0, stream>>>(cheb, Sb, x,
                                                             rk[k], k, b0);
    k_theta3<<<Bc * N, 64, 0, stream>>>(rk[0], rk[1], rk[2], Theta, sgf);
    k_final<<<Bc * N / 4, 256, 0, stream>>>(sgf, x, tcw, tcb, rcw, rcb,
                                            gam, bet, out, b0);
  }
}

// Round 5
// 1665.848 us; speedup vs baseline: 2.5378x; 1.0814x over previous
//
#include <hip/hip_runtime.h>
#include <hip/hip_bf16.h>
#include <math.h>

// ASTGCN block, MI355X. Round 5: fuse 3x Chebyshev MFMA GEMMs into one kernel
// (stage S/x once); fuse theta+conv+residual+LN into k_fuse (sg never hits
// global). Front-end attention unchanged from round 4.

namespace {

constexpr int B = 16, N = 1024, F = 32, T = 24, CC = 64, CT = 64;
constexpr int FT = F * T;     // 768
constexpr int CTT = CT * T;   // 1536

using f32x4  = __attribute__((ext_vector_type(4))) float;
using short8 = __attribute__((ext_vector_type(8))) short;

__device__ __forceinline__ float b2f(__hip_bfloat16 v) { return __bfloat162float(v); }
__device__ __forceinline__ unsigned short f2bu(float x) {   // fp32 -> bf16 bits, RNE
  union { float f; unsigned u; } c; c.f = x;
  unsigned u = c.u;
  return (unsigned short)((u + 0x7FFFu + ((u >> 16) & 1u)) >> 16);
}
__device__ __forceinline__ float us2f(unsigned short u) {   // bf16 bits -> fp32
  union { unsigned u; float f; } c; c.u = ((unsigned)u) << 16; return c.f;
}

// ---------------- temporal attention ----------------
// lhst[b,t,f] = sum_n x[b,n,f,t] * U1[n];  grid = B*T*F, block 64
__global__ void k_lhs_t(const float* x, const float* U1, float* lhst) {
  int bi = blockIdx.x;                 // (b*T+t)*F + f
  int f = bi % F; int t = (bi / F) % T; int b = bi / (F * T);
  int tid = threadIdx.x;
  float acc = 0.f;
  for (int n = tid; n < N; n += 64)
    acc += x[(((size_t)b * N + n) * F + f) * T + t] * U1[n];
  #pragma unroll
  for (int off = 32; off > 0; off >>= 1) acc += __shfl_down(acc, off);
  if (tid == 0) lhst[bi] = acc;
}

// lhs2[b,t,n] = sum_f lhst[b,t,f] * U2[f,n];  grid = B*T*N/256
__global__ void k_lhs2(const float* lhst, const float* U2, float* lhs2) {
  __shared__ float ls[F];
  int tid = threadIdx.x;
  int id = blockIdx.x * 256 + tid;   // (b*T+t)*N + n  (bt uniform per block)
  int n = id % N; int bt = id / N;
  if (tid < F) ls[tid] = lhst[bt * F + tid];
  __syncthreads();
  float acc = 0.f;
  #pragma unroll
  for (int f = 0; f < F; ++f) acc += ls[f] * U2[f * N + n];
  lhs2[id] = acc;
}

// rhst[b,n,t] = sum_f U3[f]*x[b,n,f,t];  w3x[b,n,t] = sum_f W3[f]*x[b,n,f,t]
// grid = B*N*T/256
__global__ void k_fx(const float* x, const float* U3, const float* W3,
                     float* rhst, float* w3x) {
  __shared__ float u3s[F], w3s[F];
  int tid = threadIdx.x;
  if (tid < F) { u3s[tid] = U3[tid]; w3s[tid] = W3[tid]; }
  __syncthreads();
  int id = blockIdx.x * 256 + tid;     // (b*N+n)*T + t
  int t = id % T; int bn = id / T;
  float au = 0.f, aw = 0.f;
  #pragma unroll
  for (int f = 0; f < F; ++f) {
    float v = x[((size_t)bn * F + f) * T + t];
    au += u3s[f] * v; aw += w3s[f] * v;
  }
  rhst[id] = au; w3x[id] = aw;
}

// Elog[b,t,s] = sum_n lhs2[b,t,n] * rhst[b,n,s];  grid = B*T*T, block 64
__global__ void k_Elog(const float* lhs2, const float* rhst, float* Elog) {
  int bi = blockIdx.x;                 // (b*T+t)*T + s
  int s = bi % T; int t = (bi / T) % T; int b = bi / (T * T);
  int tid = threadIdx.x;
  float acc = 0.f;
  for (int n = tid; n < N; n += 64)
    acc += lhs2[(b * T + t) * N + n] * rhst[(b * N + n) * T + s];
  #pragma unroll
  for (int off = 32; off > 0; off >>= 1) acc += __shfl_down(acc, off);
  if (tid == 0) Elog[bi] = acc;
}

// softmax over t (axis=1) for each (b,s);  grid = B, block 64
__global__ void k_Esm(const float* Elog, float* E) {
  int b = blockIdx.x; int s = threadIdx.x;
  if (s >= T) return;
  float mx = -1e30f;
  for (int t = 0; t < T; ++t) mx = fmaxf(mx, Elog[(b * T + t) * T + s]);
  float sum = 0.f;
  for (int t = 0; t < T; ++t) sum += expf(Elog[(b * T + t) * T + s] - mx);
  float inv = 1.f / sum;
  for (int t = 0; t < T; ++t)
    E[(b * T + t) * T + s] = expf(Elog[(b * T + t) * T + s] - mx) * inv;
}

// EW1[b,t] = sum_s E[b,t,s]*W1[s];  grid = B, block 64
__global__ void k_EW1(const float* E, const float* W1, float* EW1) {
  int b = blockIdx.x; int t = threadIdx.x;
  if (t >= T) return;
  float acc = 0.f;
  for (int s = 0; s < T; ++s) acc += E[(b * T + t) * T + s] * W1[s];
  EW1[b * T + t] = acc;
}

// ---------------- spatial attention (x_TAt never materialized) ----------------
// tmp1[b,n,f] = sum_t x[b,n,f,t]*EW1[b,t];  grid = B*N*F/256
__global__ void k_tmp1x(const float* x, const float* EW1, float* tmp1) {
  __shared__ float ew[T];
  int tid = threadIdx.x;
  int id = blockIdx.x * 256 + tid;       // (b*N+n)*F + f  (b uniform per block)
  int b = id / (N * F);
  if (tid < T) ew[tid] = EW1[b * T + tid];
  __syncthreads();
  const float* xr = x + (size_t)id * T;
  float acc = 0.f;
  #pragma unroll
  for (int t = 0; t < T; ++t) acc += xr[t] * ew[t];
  tmp1[id] = acc;
}

// lhss[b,n,t] = sum_f tmp1[b,n,f]*W2[f,t];  grid = B*N*T/256
__global__ void k_lhs_s(const float* tmp1, const float* W2, float* lhss) {
  int id = blockIdx.x * 256 + threadIdx.x;
  int t = id % T; int bn = id / T;
  float acc = 0.f;
  #pragma unroll
  for (int f = 0; f < F; ++f) acc += tmp1[bn * F + f] * W2[f * T + t];
  lhss[id] = acc;
}

// rhss[b,t,m] = sum_t' w3x[b,m,t'] * E[b,t',t];  grid = B*T*N/256
__global__ void k_rhss(const float* w3x, const float* E, float* rhss) {
  __shared__ float Ec[T];
  int tid = threadIdx.x;
  int id = blockIdx.x * 256 + tid;       // (b*T+t)*N + m  (t,b uniform per block)
  int m = id % N; int t = (id / N) % T; int b = id / (N * T);
  if (tid < T) Ec[tid] = E[(b * T + tid) * T + t];
  __syncthreads();
  const float* wr = w3x + ((size_t)b * N + m) * T;
  float acc = 0.f;
  #pragma unroll
  for (int tp = 0; tp < T; ++tp) acc += wr[tp] * Ec[tp];
  rhss[id] = acc;
}

// Slog[b,n,m] = sum_t lhss[b,n,t]*rhss[b,t,m]  -> bf16 logits in ws
// grid = (N/256, N/16, B), block 256
__global__ void k_Slog(const float* lhss, const float* rhss, __hip_bfloat16* S) {
  __shared__ float rt[T][256];
  __shared__ float lt[16][T];
  int m0 = blockIdx.x * 256, n0 = blockIdx.y * 16, b = blockIdx.z;
  int tid = threadIdx.x;
  for (int t = 0; t < T; ++t) rt[t][tid] = rhss[((size_t)b * T + t) * N + m0 + tid];
  for (int i = tid; i < 16 * T; i += 256) {
    int n = i / T, t = i % T;
    lt[n][t] = lhss[((size_t)b * N + n0 + n) * T + t];
  }
  __syncthreads();
  #pragma unroll 4
  for (int n = 0; n < 16; ++n) {
    float acc = 0.f;
    #pragma unroll
    for (int t = 0; t < T; ++t) acc += lt[n][t] * rt[t][tid];
    S[((size_t)b * N + n0 + n) * N + m0 + tid] = __float2bfloat16(acc);
  }
}

// in-place column softmax over n (axis=1) for each (b,m); bf16 -> bf16
// grid = (N/256, B), block 256
__global__ void k_Ssm3(__hip_bfloat16* S) {
  int m = blockIdx.x * 256 + threadIdx.x; int b = blockIdx.y;
  size_t base = (size_t)b * N * N + m;
  float mx = -1e30f;
  for (int n = 0; n < N; ++n) mx = fmaxf(mx, b2f(S[base + (size_t)n * N]));
  float sum = 0.f;
  for (int n = 0; n < N; ++n) sum += expf(b2f(S[base + (size_t)n * N]) - mx);
  float inv = 1.f / sum;
  for (int n = 0; n < N; ++n) {
    size_t i = base + (size_t)n * N;
    S[i] = __float2bfloat16(expf(b2f(S[i]) - mx) * inv);
  }
}

// ---------------- Chebyshev contraction: fused 3-k MFMA bf16 ----------------
// rhs_k[bl,m,c] = sum_n (cheb[k,n,m]*S[b,n,m]) * x[b,n,c]  for k=0,1,2
// Tile: M=64 (m), NC=128 (c), KT=64 (n). grid = (768/128, 1024/64, Bc), blk 256.
// A_l[k][m][n], X_l[c][n] k-contiguous, row stride 72 bf16 (b128-aligned).
// Stage S and x ONCE, reused across the 3 k accumulator banks.
__global__ __launch_bounds__(256) void k_gemm3(const float* cheb,
                                               const __hip_bfloat16* S,
                                               const float* x, float* rk,
                                               size_t kstride, int b0) {
  __shared__ unsigned short A_l[3 * 64 * 72];   // 27648 B
  __shared__ unsigned short X_l[128 * 72];      // 18432 B
  int bl = blockIdx.z, b = b0 + bl;
  int m0 = blockIdx.y * 64, c0 = blockIdx.x * 128;
  int tid = threadIdx.x;
  int lane = tid & 63, wid = tid >> 6;
  int l15 = tid & 15, quad = lane >> 4;

  int am = tid & 63, anq = tid >> 6;     // A: lane=m (coalesced), 16 n each
  int xc = tid & 127, xnh = tid >> 7;    // X: lane=c (coalesced), 32 n each

  f32x4 acc[3][4][2];
  #pragma unroll
  for (int k = 0; k < 3; ++k)
    #pragma unroll
    for (int i = 0; i < 4; ++i)
      #pragma unroll
      for (int j = 0; j < 2; ++j) acc[k][i][j] = (f32x4){0.f, 0.f, 0.f, 0.f};

  for (int n0 = 0; n0 < N; n0 += 64) {
    // stage A_k = cheb_k*S (bf16), transposed to [m][n]; S read once
    #pragma unroll
    for (int p = 0; p < 8; ++p) {
      int nl = anq * 16 + 2 * p;
      size_t srow = ((size_t)b * N + n0 + nl) * N + m0 + am;
      float s0 = b2f(S[srow]), s1 = b2f(S[srow + N]);
      #pragma unroll
      for (int k = 0; k < 3; ++k) {
        size_t crow = ((size_t)k * N + n0 + nl) * N + m0 + am;
        float v0 = cheb[crow] * s0;
        float v1 = cheb[crow + N] * s1;
        *(unsigned*)&A_l[k * 4608 + am * 72 + nl] =
            (unsigned)f2bu(v0) | ((unsigned)f2bu(v1) << 16);
      }
    }
    // stage X (bf16), transposed to [c][n]
    #pragma unroll
    for (int p = 0; p < 16; ++p) {
      int nl = xnh * 32 + 2 * p;
      size_t g0 = ((size_t)b * N + n0 + nl) * FT + c0 + xc;
      float v0 = x[g0];
      float v1 = x[g0 + FT];
      *(unsigned*)&X_l[xc * 72 + nl] = (unsigned)f2bu(v0) | ((unsigned)f2bu(v1) << 16);
    }
    __syncthreads();
    #pragma unroll
    for (int ks = 0; ks < 2; ++ks) {
      int nf = ks * 32 + quad * 8;
      short8 bfr[2];
      #pragma unroll
      for (int ct = 0; ct < 2; ++ct)
        bfr[ct] = *(const short8*)&X_l[(wid * 32 + ct * 16 + l15) * 72 + nf];
      #pragma unroll
      for (int k = 0; k < 3; ++k) {
        #pragma unroll
        for (int mt = 0; mt < 4; ++mt) {
          short8 af = *(const short8*)&A_l[k * 4608 + (mt * 16 + l15) * 72 + nf];
          acc[k][mt][0] = __builtin_amdgcn_mfma_f32_16x16x32_bf16(
              af, bfr[0], acc[k][mt][0], 0, 0, 0);
          acc[k][mt][1] = __builtin_amdgcn_mfma_f32_16x16x32_bf16(
              af, bfr[1], acc[k][mt][1], 0, 0, 0);
        }
      }
    }
    __syncthreads();
  }
  // epilogue: C lane map col=lane&15, row=quad*4+reg
  #pragma unroll
  for (int k = 0; k < 3; ++k)
    #pragma unroll
    for (int mt = 0; mt < 4; ++mt)
      #pragma unroll
      for (int ct = 0; ct < 2; ++ct) {
        int col = c0 + wid * 32 + ct * 16 + l15;
        #pragma unroll
        for (int r = 0; r < 4; ++r) {
          int row = m0 + mt * 16 + quad * 4 + r;
          rk[k * kstride + ((size_t)bl * N + row) * FT + col] = acc[k][mt][ct][r];
        }
      }
}

// ---------------- fused theta + relu + time-conv + residual + relu + LN ------
// block 256 = 4 waves = 4 rows (m); lane = o = ct. grid = Bc*N/4.
// sg lives only in LDS (row_l region reused after theta).
__global__ __launch_bounds__(256) void k_fuse(const float* rk, size_t kstride,
                                              const float* x, const float* Theta,
                                              const float* tcw, const float* tcb,
                                              const float* rcw, const float* rcb,
                                              const float* gam, const float* bet,
                                              float* out, int b0) {
  __shared__ unsigned short Th_l[96 * 66];     // 12672 B  [kf][o]
  __shared__ unsigned short tcw_l[192 * 66];   // 25344 B  [cc3][ct]
  __shared__ unsigned short rcw_l[32 * 66];    //  4224 B  [f][ct]
  __shared__ __align__(16) float row_l[4 * 2304];  // 36864 B; reused for sg
  int tid = threadIdx.x;
  int w = tid >> 6, o = tid & 63;
  int r0l = blockIdx.x * 4;                    // chunk-local row base

  for (int g = tid; g < 96 * 64; g += 256)
    Th_l[(g >> 6) * 66 + (g & 63)] = f2bu(Theta[g]);
  for (int g = tid; g < CT * 192; g += 256) {
    int ct = g / 192, r = g % 192;
    tcw_l[r * 66 + ct] = f2bu(tcw[g]);
  }
  for (int g = tid; g < CT * F; g += 256) {
    int ct = g / F, f = g % F;
    rcw_l[f * 66 + ct] = f2bu(rcw[g]);
  }
  for (int i = tid; i < 4 * 2304; i += 256) {
    int r = i / 2304, j = i % 2304;
    int k = j / FT, c = j % FT;
    row_l[i] = rk[k * kstride + ((size_t)(r0l + r)) * FT + c];
  }
  __syncthreads();

  // ---- theta: sg[o][t] = relu(sum_{k,f} rhs_k[m,f,t]*Theta[k,f,o])
  // row offset for (k,f) is k*768+f*24 = 24*kf
  float sg[T];
  #pragma unroll
  for (int t = 0; t < T; ++t) sg[t] = 0.f;
  const float* rw = &row_l[w * 2304];
  #pragma unroll 8
  for (int kf = 0; kf < 96; ++kf) {
    float th = us2f(Th_l[kf * 66 + o]);
    const float4* rp = (const float4*)&rw[kf * 24];
    #pragma unroll
    for (int q = 0; q < 6; ++q) {
      float4 v = rp[q];
      sg[q * 4 + 0] += th * v.x; sg[q * 4 + 1] += th * v.y;
      sg[q * 4 + 2] += th * v.z; sg[q * 4 + 3] += th * v.w;
    }
  }
  #pragma unroll
  for (int t = 0; t < T; ++t) sg[t] = fmaxf(sg[t], 0.f);
  __syncthreads();
  // write sg into own wave's (now dead) row_l region: [o*24 + t]
  float* sgl = &row_l[w * 2304];
  #pragma unroll
  for (int q = 0; q < 6; ++q)
    ((float4*)&sgl[o * 24])[q] =
        make_float4(sg[q * 4], sg[q * 4 + 1], sg[q * 4 + 2], sg[q * 4 + 3]);
  __syncthreads();

  // ---- time conv (1,3) pad (0,1) + residual + relu + LN
  float acc[T];
  float bias = tcb[o] + rcb[o];
  #pragma unroll
  for (int t = 0; t < T; ++t) acc[t] = bias;

  #pragma unroll 4
  for (int cc = 0; cc < CC; ++cc) {
    float w0 = us2f(tcw_l[(cc * 3 + 0) * 66 + o]);
    float w1 = us2f(tcw_l[(cc * 3 + 1) * 66 + o]);
    float w2 = us2f(tcw_l[(cc * 3 + 2) * 66 + o]);
    const float4* sp = (const float4*)&sgl[cc * 24];
    float sv[T];
    #pragma unroll
    for (int q = 0; q < 6; ++q) {
      float4 v = sp[q];
      sv[q * 4 + 0] = v.x; sv[q * 4 + 1] = v.y;
      sv[q * 4 + 2] = v.z; sv[q * 4 + 3] = v.w;
    }
    acc[0] += w1 * sv[0] + w2 * sv[1];
    #pragma unroll
    for (int t = 1; t < T - 1; ++t)
      acc[t] += w0 * sv[t - 1] + w1 * sv[t] + w2 * sv[t + 1];
    acc[T - 1] += w0 * sv[T - 2] + w1 * sv[T - 1];
  }
  // residual 1x1 from x (wave-uniform row -> broadcast loads)
  size_t grow = (size_t)b0 * N + r0l + w;
  const float* xrow = x + grow * FT;
  #pragma unroll 4
  for (int f = 0; f < F; ++f) {
    float wf = us2f(rcw_l[f * 66 + o]);
    const float4* xp = (const float4*)&xrow[f * 24];
    #pragma unroll
    for (int q = 0; q < 6; ++q) {
      float4 v = xp[q];
      acc[q * 4 + 0] += wf * v.x; acc[q * 4 + 1] += wf * v.y;
      acc[q * 4 + 2] += wf * v.z; acc[q * 4 + 3] += wf * v.w;
    }
  }
  // relu + LN over the 64 lanes (ct) per t
  float g = gam[o], be = bet[o];
  float ov[T];
  #pragma unroll
  for (int t = 0; t < T; ++t) {
    float z = fmaxf(acc[t], 0.f);
    float s = z, q = z * z;
    #pragma unroll
    for (int off = 1; off < 64; off <<= 1) {
      s += __shfl_xor(s, off);
      q += __shfl_xor(q, off);
    }
    float mu = s * (1.f / 64.f);
    float var = q * (1.f / 64.f) - mu * mu;
    ov[t] = (z - mu) * rsqrtf(var + 1e-5f) * g + be;
  }
  float* orow = out + grow * CTT + o * T;
  #pragma unroll
  for (int q = 0; q < 6; ++q)
    ((float4*)orow)[q] =
        make_float4(ov[q * 4], ov[q * 4 + 1], ov[q * 4 + 2], ov[q * 4 + 3]);
}

}  // namespace

extern "C" void kernel_launch(void* const* d_in, const int* in_sizes, int n_in,
                              void* d_out, int out_size, void* d_ws, size_t ws_size,
                              hipStream_t stream) {
  (void)in_sizes; (void)n_in; (void)out_size;
  const float* x     = (const float*)d_in[0];
  const float* W1    = (const float*)d_in[1];
  const float* W2    = (const float*)d_in[2];
  const float* W3    = (const float*)d_in[3];
  const float* U1    = (const float*)d_in[4];
  const float* U2    = (const float*)d_in[5];
  const float* U3    = (const float*)d_in[6];
  const float* cheb  = (const float*)d_in[7];
  const float* Theta = (const float*)d_in[8];
  const float* tcw   = (const float*)d_in[9];
  const float* tcb   = (const float*)d_in[10];
  const float* rcw   = (const float*)d_in[11];
  const float* rcb   = (const float*)d_in[12];
  const float* gam   = (const float*)d_in[13];
  const float* bet   = (const float*)d_in[14];
  float* out = (float*)d_out;

  // ---- runtime-adaptive workspace layout ----
  const size_t SB_BYTES = (size_t)B * N * N * 2;          // 33,554,432 (S bf16)
  const size_t RK_PER_B = (size_t)N * FT * 4;             // 3,145,728 (x3 buffers)
  const size_t SMALL_FLOATS = 2521472;
  int Bc = 16;
  while (Bc > 1 &&
         SB_BYTES + (size_t)Bc * 3 * RK_PER_B + SMALL_FLOATS * 4 > ws_size)
    Bc >>= 1;

  char* w = (char*)d_ws;
  __hip_bfloat16* Sb = (__hip_bfloat16*)w;
  float* rkbuf = (float*)(w + SB_BYTES);
  size_t kstride = (size_t)Bc * N * FT;       // floats per k-bank
  float* sm = (float*)(w + SB_BYTES + (size_t)Bc * 3 * RK_PER_B);
  float* lhst = sm;                       // B*T*F   = 12288
  float* lhs2 = lhst + B * T * F;         // B*T*N   = 393216
  float* rhst = lhs2 + B * T * N;         // B*N*T   = 393216
  float* w3x  = rhst + B * N * T;         // B*N*T   = 393216
  float* Elog = w3x + B * N * T;          // B*T*T   = 9216
  float* E    = Elog + B * T * T;         // B*T*T   = 9216
  float* EW1  = E + B * T * T;            // B*T     = 384
  float* tmp1 = EW1 + B * T;              // B*N*F   = 524288
  float* lhss = tmp1 + B * N * F;         // B*N*T   = 393216
  float* rhss = lhss + B * N * T;         // B*N*T   = 393216

  // temporal attention
  k_lhs_t<<<B * T * F, 64, 0, stream>>>(x, U1, lhst);
  k_lhs2<<<(B * T * N) / 256, 256, 0, stream>>>(lhst, U2, lhs2);
  k_fx<<<(B * N * T) / 256, 256, 0, stream>>>(x, U3, W3, rhst, w3x);
  k_Elog<<<B * T * T, 64, 0, stream>>>(lhs2, rhst, Elog);
  k_Esm<<<B, 64, 0, stream>>>(Elog, E);
  k_EW1<<<B, 64, 0, stream>>>(E, W1, EW1);

  // spatial attention (x_TAt folded out)
  k_tmp1x<<<(B * N * F) / 256, 256, 0, stream>>>(x, EW1, tmp1);
  k_lhs_s<<<(B * N * T) / 256, 256, 0, stream>>>(tmp1, W2, lhss);
  k_rhss<<<(B * N * T) / 256, 256, 0, stream>>>(w3x, E, rhss);
  k_Slog<<<dim3(N / 256, N / 16, B), 256, 0, stream>>>(lhss, rhss, Sb);
  k_Ssm3<<<dim3(N / 256, B), 256, 0, stream>>>(Sb);

  // fused 3-k chebyshev MFMA GEMM + fused theta/conv/LN, chunked over b
  for (int b0 = 0; b0 < B; b0 += Bc) {
    k_gemm3<<<dim3(FT / 128, N / 64, Bc), 256, 0, stream>>>(cheb, Sb, x, rkbuf,
                                                            kstride, b0);
    k_fuse<<<Bc * N / 4, 256, 0, stream>>>(rkbuf, kstride, x, Theta, tcw, tcb,
                                           rcw, rcb, gam, bet, out, b0);
  }
}

// Round 6
// 1278.955 us; speedup vs baseline: 3.3056x; 1.3025x over previous
//
#include <hip/hip_runtime.h>
#include <hip/hip_bf16.h>
#include <math.h>

// ASTGCN block, MI355X. Round 6: pre-transposed bf16 GEMM operands
// (k_prepA/k_prepX) so k_gemm3 staging is pure 16B copies; k_fuse weights
// pre-converted bf16 (k_prepW) for copy-only staging. Front-end unchanged.

namespace {

constexpr int B = 16, N = 1024, F = 32, T = 24, CC = 64, CT = 64;
constexpr int FT = F * T;     // 768
constexpr int CTT = CT * T;   // 1536

using f32x4  = __attribute__((ext_vector_type(4))) float;
using short8 = __attribute__((ext_vector_type(8))) short;

__device__ __forceinline__ float b2f(__hip_bfloat16 v) { return __bfloat162float(v); }
__device__ __forceinline__ unsigned short f2bu(float x) {   // fp32 -> bf16 bits, RNE
  union { float f; unsigned u; } c; c.f = x;
  unsigned u = c.u;
  return (unsigned short)((u + 0x7FFFu + ((u >> 16) & 1u)) >> 16);
}
__device__ __forceinline__ float us2f(unsigned short u) {   // bf16 bits -> fp32
  union { unsigned u; float f; } c; c.u = ((unsigned)u) << 16; return c.f;
}

// ---------------- temporal attention ----------------
__global__ void k_lhs_t(const float* x, const float* U1, float* lhst) {
  int bi = blockIdx.x;                 // (b*T+t)*F + f
  int f = bi % F; int t = (bi / F) % T; int b = bi / (F * T);
  int tid = threadIdx.x;
  float acc = 0.f;
  for (int n = tid; n < N; n += 64)
    acc += x[(((size_t)b * N + n) * F + f) * T + t] * U1[n];
  #pragma unroll
  for (int off = 32; off > 0; off >>= 1) acc += __shfl_down(acc, off);
  if (tid == 0) lhst[bi] = acc;
}

__global__ void k_lhs2(const float* lhst, const float* U2, float* lhs2) {
  __shared__ float ls[F];
  int tid = threadIdx.x;
  int id = blockIdx.x * 256 + tid;   // (b*T+t)*N + n
  int n = id % N; int bt = id / N;
  if (tid < F) ls[tid] = lhst[bt * F + tid];
  __syncthreads();
  float acc = 0.f;
  #pragma unroll
  for (int f = 0; f < F; ++f) acc += ls[f] * U2[f * N + n];
  lhs2[id] = acc;
}

__global__ void k_fx(const float* x, const float* U3, const float* W3,
                     float* rhst, float* w3x) {
  __shared__ float u3s[F], w3s[F];
  int tid = threadIdx.x;
  if (tid < F) { u3s[tid] = U3[tid]; w3s[tid] = W3[tid]; }
  __syncthreads();
  int id = blockIdx.x * 256 + tid;     // (b*N+n)*T + t
  int t = id % T; int bn = id / T;
  float au = 0.f, aw = 0.f;
  #pragma unroll
  for (int f = 0; f < F; ++f) {
    float v = x[((size_t)bn * F + f) * T + t];
    au += u3s[f] * v; aw += w3s[f] * v;
  }
  rhst[id] = au; w3x[id] = aw;
}

__global__ void k_Elog(const float* lhs2, const float* rhst, float* Elog) {
  int bi = blockIdx.x;                 // (b*T+t)*T + s
  int s = bi % T; int t = (bi / T) % T; int b = bi / (T * T);
  int tid = threadIdx.x;
  float acc = 0.f;
  for (int n = tid; n < N; n += 64)
    acc += lhs2[(b * T + t) * N + n] * rhst[(b * N + n) * T + s];
  #pragma unroll
  for (int off = 32; off > 0; off >>= 1) acc += __shfl_down(acc, off);
  if (tid == 0) Elog[bi] = acc;
}

__global__ void k_Esm(const float* Elog, float* E) {
  int b = blockIdx.x; int s = threadIdx.x;
  if (s >= T) return;
  float mx = -1e30f;
  for (int t = 0; t < T; ++t) mx = fmaxf(mx, Elog[(b * T + t) * T + s]);
  float sum = 0.f;
  for (int t = 0; t < T; ++t) sum += expf(Elog[(b * T + t) * T + s] - mx);
  float inv = 1.f / sum;
  for (int t = 0; t < T; ++t)
    E[(b * T + t) * T + s] = expf(Elog[(b * T + t) * T + s] - mx) * inv;
}

__global__ void k_EW1(const float* E, const float* W1, float* EW1) {
  int b = blockIdx.x; int t = threadIdx.x;
  if (t >= T) return;
  float acc = 0.f;
  for (int s = 0; s < T; ++s) acc += E[(b * T + t) * T + s] * W1[s];
  EW1[b * T + t] = acc;
}

// ---------------- spatial attention ----------------
__global__ void k_tmp1x(const float* x, const float* EW1, float* tmp1) {
  __shared__ float ew[T];
  int tid = threadIdx.x;
  int id = blockIdx.x * 256 + tid;       // (b*N+n)*F + f
  int b = id / (N * F);
  if (tid < T) ew[tid] = EW1[b * T + tid];
  __syncthreads();
  const float* xr = x + (size_t)id * T;
  float acc = 0.f;
  #pragma unroll
  for (int t = 0; t < T; ++t) acc += xr[t] * ew[t];
  tmp1[id] = acc;
}

__global__ void k_lhs_s(const float* tmp1, const float* W2, float* lhss) {
  int id = blockIdx.x * 256 + threadIdx.x;
  int t = id % T; int bn = id / T;
  float acc = 0.f;
  #pragma unroll
  for (int f = 0; f < F; ++f) acc += tmp1[bn * F + f] * W2[f * T + t];
  lhss[id] = acc;
}

__global__ void k_rhss(const float* w3x, const float* E, float* rhss) {
  __shared__ float Ec[T];
  int tid = threadIdx.x;
  int id = blockIdx.x * 256 + tid;       // (b*T+t)*N + m
  int m = id % N; int t = (id / N) % T; int b = id / (N * T);
  if (tid < T) Ec[tid] = E[(b * T + tid) * T + t];
  __syncthreads();
  const float* wr = w3x + ((size_t)b * N + m) * T;
  float acc = 0.f;
  #pragma unroll
  for (int tp = 0; tp < T; ++tp) acc += wr[tp] * Ec[tp];
  rhss[id] = acc;
}

__global__ void k_Slog(const float* lhss, const float* rhss, __hip_bfloat16* S) {
  __shared__ float rt[T][256];
  __shared__ float lt[16][T];
  int m0 = blockIdx.x * 256, n0 = blockIdx.y * 16, b = blockIdx.z;
  int tid = threadIdx.x;
  for (int t = 0; t < T; ++t) rt[t][tid] = rhss[((size_t)b * T + t) * N + m0 + tid];
  for (int i = tid; i < 16 * T; i += 256) {
    int n = i / T, t = i % T;
    lt[n][t] = lhss[((size_t)b * N + n0 + n) * T + t];
  }
  __syncthreads();
  #pragma unroll 4
  for (int n = 0; n < 16; ++n) {
    float acc = 0.f;
    #pragma unroll
    for (int t = 0; t < T; ++t) acc += lt[n][t] * rt[t][tid];
    S[((size_t)b * N + n0 + n) * N + m0 + tid] = __float2bfloat16(acc);
  }
}

__global__ void k_Ssm3(__hip_bfloat16* S) {
  int m = blockIdx.x * 256 + threadIdx.x; int b = blockIdx.y;
  size_t base = (size_t)b * N * N + m;
  float mx = -1e30f;
  for (int n = 0; n < N; ++n) mx = fmaxf(mx, b2f(S[base + (size_t)n * N]));
  float sum = 0.f;
  for (int n = 0; n < N; ++n) sum += expf(b2f(S[base + (size_t)n * N]) - mx);
  float inv = 1.f / sum;
  for (int n = 0; n < N; ++n) {
    size_t i = base + (size_t)n * N;
    S[i] = __float2bfloat16(expf(b2f(S[i]) - mx) * inv);
  }
}

// ---------------- GEMM operand prep (transpose to n-contiguous bf16) --------
// Abf[(k*Bc+bl)][m][n] = bf16(cheb[k,n,m] * S[b,n,m]); grid (N/64, N/64, 3*Bc)
__global__ __launch_bounds__(256) void k_prepA(const float* cheb,
                                               const __hip_bfloat16* S,
                                               unsigned short* Abf,
                                               int Bc, int b0) {
  __shared__ float Tl[64][65];
  int z = blockIdx.z;
  int k = z / Bc, bl = z % Bc, b = b0 + bl;
  int n0 = blockIdx.x * 64, m0 = blockIdx.y * 64;
  int tid = threadIdx.x;
  int j = tid & 63, i4 = tid >> 6;
  #pragma unroll
  for (int it = 0; it < 16; ++it) {
    int i = it * 4 + i4;
    Tl[i][j] = cheb[((size_t)k * N + n0 + i) * N + m0 + j] *
               b2f(S[((size_t)b * N + n0 + i) * N + m0 + j]);
  }
  __syncthreads();
  int i2 = (tid & 31) * 2, j8 = tid >> 5;
  #pragma unroll
  for (int it = 0; it < 8; ++it) {
    int jj = it * 8 + j8;
    unsigned u = (unsigned)f2bu(Tl[i2][jj]) | ((unsigned)f2bu(Tl[i2 + 1][jj]) << 16);
    *(unsigned*)&Abf[((size_t)z * N + m0 + jj) * N + n0 + i2] = u;
  }
}

// xT[bl][c][n] = bf16(x[b,n,c]); grid (N/64, FT/64=12, Bc)
__global__ __launch_bounds__(256) void k_prepX(const float* x, unsigned short* xT,
                                               int b0) {
  __shared__ float Tl[64][65];
  int bl = blockIdx.z, b = b0 + bl;
  int n0 = blockIdx.x * 64, c0 = blockIdx.y * 64;
  int tid = threadIdx.x;
  int j = tid & 63, i4 = tid >> 6;
  #pragma unroll
  for (int it = 0; it < 16; ++it) {
    int i = it * 4 + i4;
    Tl[i][j] = x[((size_t)b * N + n0 + i) * FT + c0 + j];
  }
  __syncthreads();
  int i2 = (tid & 31) * 2, j8 = tid >> 5;
  #pragma unroll
  for (int it = 0; it < 8; ++it) {
    int jj = it * 8 + j8;
    unsigned u = (unsigned)f2bu(Tl[i2][jj]) | ((unsigned)f2bu(Tl[i2 + 1][jj]) << 16);
    *(unsigned*)&xT[((size_t)bl * FT + c0 + jj) * N + n0 + i2] = u;
  }
}

// weights -> bf16, pre-transposed layouts for k_fuse. one block.
// wbf: Th [kf*64+o] (0..6143), tcw [(cc*3+j)*64+ct] (6144..18431),
//      rcw [f*64+ct] (18432..20479)
__global__ void k_prepW(const float* Theta, const float* tcw, const float* rcw,
                        unsigned short* wbf) {
  int tid = threadIdx.x;
  for (int g = tid; g < 96 * 64; g += 256) wbf[g] = f2bu(Theta[g]);
  for (int g = tid; g < 192 * 64; g += 256) {
    int r = g >> 6, ct = g & 63;
    wbf[6144 + g] = f2bu(tcw[ct * 192 + r]);
  }
  for (int g = tid; g < 32 * 64; g += 256) {
    int r = g >> 6, ct = g & 63;
    wbf[18432 + g] = f2bu(rcw[ct * 32 + r]);
  }
}

// ---------------- Chebyshev contraction: fused 3-k MFMA bf16 v2 -------------
// Both operands bf16, n-contiguous. Staging = pure 16B copies.
// Tile 64m x 128c x 64n; waves 2x2 (32m x 64c each). grid (6, 16, Bc).
__global__ __launch_bounds__(256) void k_gemm3(const unsigned short* Abf,
                                               const unsigned short* xT,
                                               float* rk, size_t kstride,
                                               int Bc) {
  __shared__ __align__(16) unsigned short A_l[3 * 64 * 72];   // 27648 B
  __shared__ __align__(16) unsigned short X_l[128 * 72];      // 18432 B
  int bl = blockIdx.z;
  int m0 = blockIdx.y * 64, c0 = blockIdx.x * 128;
  int tid = threadIdx.x;
  int lane = tid & 63, w = tid >> 6;
  int l15 = lane & 15, quad = lane >> 4;
  int wmi = w & 1, wci = w >> 1;
  int nh = lane & 7, ml = lane >> 3;

  f32x4 acc[3][2][4];
  #pragma unroll
  for (int k = 0; k < 3; ++k)
    #pragma unroll
    for (int mt = 0; mt < 2; ++mt)
      #pragma unroll
      for (int ct = 0; ct < 4; ++ct) acc[k][mt][ct] = (f32x4){0.f, 0.f, 0.f, 0.f};

  for (int n0 = 0; n0 < N; n0 += 64) {
    #pragma unroll
    for (int it = 0; it < 6; ++it) {               // A: 3k x 64m x 64n
      int k = it >> 1, mh = it & 1;
      int m = mh * 32 + w * 8 + ml;
      *(uint4*)&A_l[(k * 64 + m) * 72 + nh * 8] =
          *(const uint4*)&Abf[((size_t)(k * Bc + bl) * N + m0 + m) * N + n0 + nh * 8];
    }
    #pragma unroll
    for (int it = 0; it < 4; ++it) {               // X: 128c x 64n
      int c = it * 32 + w * 8 + ml;
      *(uint4*)&X_l[c * 72 + nh * 8] =
          *(const uint4*)&xT[((size_t)bl * FT + c0 + c) * N + n0 + nh * 8];
    }
    __syncthreads();
    #pragma unroll
    for (int ks = 0; ks < 2; ++ks) {
      int nf = ks * 32 + quad * 8;
      short8 bfr[4];
      #pragma unroll
      for (int ct = 0; ct < 4; ++ct)
        bfr[ct] = *(const short8*)&X_l[(wci * 64 + ct * 16 + l15) * 72 + nf];
      #pragma unroll
      for (int k = 0; k < 3; ++k)
        #pragma unroll
        for (int mt = 0; mt < 2; ++mt) {
          short8 af = *(const short8*)&A_l[(k * 64 + wmi * 32 + mt * 16 + l15) * 72 + nf];
          #pragma unroll
          for (int ct = 0; ct < 4; ++ct)
            acc[k][mt][ct] = __builtin_amdgcn_mfma_f32_16x16x32_bf16(
                af, bfr[ct], acc[k][mt][ct], 0, 0, 0);
        }
    }
    __syncthreads();
  }
  #pragma unroll
  for (int k = 0; k < 3; ++k)
    #pragma unroll
    for (int mt = 0; mt < 2; ++mt)
      #pragma unroll
      for (int ct = 0; ct < 4; ++ct) {
        int col = c0 + wci * 64 + ct * 16 + l15;
        #pragma unroll
        for (int r = 0; r < 4; ++r) {
          int row = m0 + wmi * 32 + mt * 16 + quad * 4 + r;
          rk[k * kstride + ((size_t)bl * N + row) * FT + col] = acc[k][mt][ct][r];
        }
      }
}

// ---------------- fused theta + relu + conv + residual + relu + LN ----------
// block 256 = 4 waves = 4 rows; lane = o = ct. grid = Bc*N/4.
__global__ __launch_bounds__(256) void k_fuse(const float* rk, size_t kstride,
                                              const float* x,
                                              const unsigned short* wbf,
                                              const float* tcb, const float* rcb,
                                              const float* gam, const float* bet,
                                              float* out, int b0) {
  __shared__ __align__(16) unsigned short W_l[20480];   // 40960 B
  __shared__ __align__(16) float row_l[4 * 2304];       // 36864 B (sg reuses)
  int tid = threadIdx.x;
  int w = tid >> 6, o = tid & 63;
  int r0l = blockIdx.x * 4;

  #pragma unroll
  for (int it = 0; it < 10; ++it) {      // weights: 2560 x 16B pure copy
    int ch = it * 256 + tid;
    *(uint4*)&W_l[ch * 8] = *(const uint4*)&wbf[ch * 8];
  }
  #pragma unroll
  for (int it = 0; it < 9; ++it) {       // rows: 2304 x 16B
    int ch = it * 256 + tid;
    int r = ch / 576, rem = ch % 576;
    int k = rem / 192, c4 = rem % 192;
    *(uint4*)&row_l[ch * 4] =
        *(const uint4*)&rk[(size_t)k * kstride + (size_t)(r0l + r) * FT + c4 * 4];
  }
  __syncthreads();

  // theta: sg[o][t] = relu(sum_kf rhs[m][kf*24+t] * Th[kf][o])
  float sg[T];
  #pragma unroll
  for (int t = 0; t < T; ++t) sg[t] = 0.f;
  const float* rw = &row_l[w * 2304];
  #pragma unroll 8
  for (int kf = 0; kf < 96; ++kf) {
    float th = us2f(W_l[kf * 64 + o]);
    const float4* rp = (const float4*)&rw[kf * 24];
    #pragma unroll
    for (int q = 0; q < 6; ++q) {
      float4 v = rp[q];
      sg[q * 4 + 0] += th * v.x; sg[q * 4 + 1] += th * v.y;
      sg[q * 4 + 2] += th * v.z; sg[q * 4 + 3] += th * v.w;
    }
  }
  // per-wave private sg region (stride 28, 1792 floats <= 2304): no barrier
  // needed — wave only touches its own region.
  float* sgl = &row_l[w * 2304];
  #pragma unroll
  for (int q = 0; q < 6; ++q)
    ((float4*)&sgl[o * 28])[q] =
        make_float4(fmaxf(sg[q * 4], 0.f), fmaxf(sg[q * 4 + 1], 0.f),
                    fmaxf(sg[q * 4 + 2], 0.f), fmaxf(sg[q * 4 + 3], 0.f));

  // time conv (1,3) pad (0,1) + residual + relu + LN
  float acc[T];
  float bias = tcb[o] + rcb[o];
  #pragma unroll
  for (int t = 0; t < T; ++t) acc[t] = bias;

  #pragma unroll 4
  for (int cc = 0; cc < CC; ++cc) {
    float w0 = us2f(W_l[6144 + (cc * 3 + 0) * 64 + o]);
    float w1 = us2f(W_l[6144 + (cc * 3 + 1) * 64 + o]);
    float w2 = us2f(W_l[6144 + (cc * 3 + 2) * 64 + o]);
    const float4* sp = (const float4*)&sgl[cc * 28];   // wave-uniform broadcast
    float sv[T];
    #pragma unroll
    for (int q = 0; q < 6; ++q) {
      float4 v = sp[q];
      sv[q * 4 + 0] = v.x; sv[q * 4 + 1] = v.y;
      sv[q * 4 + 2] = v.z; sv[q * 4 + 3] = v.w;
    }
    acc[0] += w1 * sv[0] + w2 * sv[1];
    #pragma unroll
    for (int t = 1; t < T - 1; ++t)
      acc[t] += w0 * sv[t - 1] + w1 * sv[t] + w2 * sv[t + 1];
    acc[T - 1] += w0 * sv[T - 2] + w1 * sv[T - 1];
  }
  size_t grow = (size_t)b0 * N + r0l + w;
  const float* xrow = x + grow * FT;
  #pragma unroll 4
  for (int f = 0; f < F; ++f) {
    float wf = us2f(W_l[18432 + f * 64 + o]);
    const float4* xp = (const float4*)&xrow[f * 24];   // wave-uniform broadcast
    #pragma unroll
    for (int q = 0; q < 6; ++q) {
      float4 v = xp[q];
      acc[q * 4 + 0] += wf * v.x; acc[q * 4 + 1] += wf * v.y;
      acc[q * 4 + 2] += wf * v.z; acc[q * 4 + 3] += wf * v.w;
    }
  }
  float g = gam[o], be = bet[o];
  float ov[T];
  #pragma unroll
  for (int t = 0; t < T; ++t) {
    float z = fmaxf(acc[t], 0.f);
    float s = z, q = z * z;
    #pragma unroll
    for (int off = 1; off < 64; off <<= 1) {
      s += __shfl_xor(s, off);
      q += __shfl_xor(q, off);
    }
    float mu = s * (1.f / 64.f);
    float var = q * (1.f / 64.f) - mu * mu;
    ov[t] = (z - mu) * rsqrtf(var + 1e-5f) * g + be;
  }
  float* orow = out + grow * CTT + o * T;
  #pragma unroll
  for (int q = 0; q < 6; ++q)
    ((float4*)orow)[q] =
        make_float4(ov[q * 4], ov[q * 4 + 1], ov[q * 4 + 2], ov[q * 4 + 3]);
}

}  // namespace

extern "C" void kernel_launch(void* const* d_in, const int* in_sizes, int n_in,
                              void* d_out, int out_size, void* d_ws, size_t ws_size,
                              hipStream_t stream) {
  (void)in_sizes; (void)n_in; (void)out_size;
  const float* x     = (const float*)d_in[0];
  const float* W1    = (const float*)d_in[1];
  const float* W2    = (const float*)d_in[2];
  const float* W3    = (const float*)d_in[3];
  const float* U1    = (const float*)d_in[4];
  const float* U2    = (const float*)d_in[5];
  const float* U3    = (const float*)d_in[6];
  const float* cheb  = (const float*)d_in[7];
  const float* Theta = (const float*)d_in[8];
  const float* tcw   = (const float*)d_in[9];
  const float* tcb   = (const float*)d_in[10];
  const float* rcw   = (const float*)d_in[11];
  const float* rcb   = (const float*)d_in[12];
  const float* gam   = (const float*)d_in[13];
  const float* bet   = (const float*)d_in[14];
  float* out = (float*)d_out;

  // ---- runtime-adaptive workspace layout ----
  const size_t SB_BYTES = (size_t)B * N * N * 2;          // 33,554,432 (S bf16)
  const size_t WB_BYTES = 65536;                          // wbf (40960 used)
  const size_t AB_PER_B = (size_t)3 * N * N * 2;          // 6,291,456
  const size_t XT_PER_B = (size_t)FT * N * 2;             // 1,572,864
  const size_t RK_PER_B = (size_t)3 * N * FT * 4;         // 9,437,184
  const size_t SMALL = 2521472 * 4;                       // 10,085,888 B
  int Bc = 16;
  while (Bc > 1 && SB_BYTES + WB_BYTES + SMALL +
             (size_t)Bc * (AB_PER_B + XT_PER_B + RK_PER_B) > ws_size)
    Bc >>= 1;

  char* w = (char*)d_ws;
  __hip_bfloat16* Sb = (__hip_bfloat16*)w;
  unsigned short* wbf = (unsigned short*)(w + SB_BYTES);
  unsigned short* Abf = (unsigned short*)(w + SB_BYTES + WB_BYTES);
  unsigned short* xTb = (unsigned short*)(w + SB_BYTES + WB_BYTES +
                                          (size_t)Bc * AB_PER_B);
  float* rkbuf = (float*)(w + SB_BYTES + WB_BYTES +
                          (size_t)Bc * (AB_PER_B + XT_PER_B));
  size_t kstride = (size_t)Bc * N * FT;     // floats per k-bank of rk
  float* sm = (float*)(w + SB_BYTES + WB_BYTES +
                       (size_t)Bc * (AB_PER_B + XT_PER_B + RK_PER_B));
  float* lhst = sm;                       // B*T*F   = 12288
  float* lhs2 = lhst + B * T * F;         // B*T*N   = 393216
  float* rhst = lhs2 + B * T * N;         // B*N*T   = 393216
  float* w3x  = rhst + B * N * T;         // B*N*T   = 393216
  float* Elog = w3x + B * N * T;          // B*T*T   = 9216
  float* E    = Elog + B * T * T;         // B*T*T   = 9216
  float* EW1  = E + B * T * T;            // B*T     = 384
  float* tmp1 = EW1 + B * T;              // B*N*F   = 524288
  float* lhss = tmp1 + B * N * F;         // B*N*T   = 393216
  float* rhss = lhss + B * N * T;         // B*N*T   = 393216

  // temporal attention
  k_lhs_t<<<B * T * F, 64, 0, stream>>>(x, U1, lhst);
  k_lhs2<<<(B * T * N) / 256, 256, 0, stream>>>(lhst, U2, lhs2);
  k_fx<<<(B * N * T) / 256, 256, 0, stream>>>(x, U3, W3, rhst, w3x);
  k_Elog<<<B * T * T, 64, 0, stream>>>(lhs2, rhst, Elog);
  k_Esm<<<B, 64, 0, stream>>>(Elog, E);
  k_EW1<<<B, 64, 0, stream>>>(E, W1, EW1);

  // spatial attention (x_TAt folded out)
  k_tmp1x<<<(B * N * F) / 256, 256, 0, stream>>>(x, EW1, tmp1);
  k_lhs_s<<<(B * N * T) / 256, 256, 0, stream>>>(tmp1, W2, lhss);
  k_rhss<<<(B * N * T) / 256, 256, 0, stream>>>(w3x, E, rhss);
  k_Slog<<<dim3(N / 256, N / 16, B), 256, 0, stream>>>(lhss, rhss, Sb);
  k_Ssm3<<<dim3(N / 256, B), 256, 0, stream>>>(Sb);

  // weight prep (once)
  k_prepW<<<1, 256, 0, stream>>>(Theta, tcw, rcw, wbf);

  // per-chunk: operand prep + fused GEMM + fused epilogue
  for (int b0 = 0; b0 < B; b0 += Bc) {
    k_prepA<<<dim3(N / 64, N / 64, 3 * Bc), 256, 0, stream>>>(cheb, Sb, Abf, Bc, b0);
    k_prepX<<<dim3(N / 64, FT / 64, Bc), 256, 0, stream>>>(x, xTb, b0);
    k_gemm3<<<dim3(FT / 128, N / 64, Bc), 256, 0, stream>>>(Abf, xTb, rkbuf,
                                                            kstride, Bc);
    k_fuse<<<Bc * N / 4, 256, 0, stream>>>(rkbuf, kstride, x, wbf, tcb, rcb,
                                           gam, bet, out, b0);
  }
}